// Round 3
// baseline (748.812 us; speedup 1.0000x reference)
//
#include <hip/hip_runtime.h>

#define S_LEN 16
#define NMODEL 4096
#define DHEAD 128
#define HHEADS 32
#define MCACHE 8192
#define SPLITK 16
#define KSLICE (NMODEL / SPLITK)   // 256
#define CHUNK 256
#define NCHUNK (MCACHE / CHUNK)    // 32
#define SCPAD 20                   // 80-byte rows: 16B-aligned, b128-friendly

// ---------------- Kernel 1: split-K partial QKV projection ----------------
// (unchanged from round 2 — working, ~coalesced weight stream)
__global__ __launch_bounds__(256) void qkv_gemm(const float* __restrict__ X,
                                                const float* __restrict__ Wq,
                                                const float* __restrict__ Wk,
                                                const float* __restrict__ Wv,
                                                float* __restrict__ part) {
    const int tid   = threadIdx.x;
    const int col2  = blockIdx.x * 256 + tid;
    const int split = blockIdx.y;
    const int mat   = blockIdx.z;
    const float* __restrict__ W = (mat == 0) ? Wq : (mat == 1) ? Wk : Wv;
    const int k0 = split * KSLICE;

    __shared__ float Xs[KSLICE][S_LEN];
    for (int i = tid; i < KSLICE * S_LEN; i += 256) {
        const int s = i & 15, k = i >> 4;
        Xs[k][s] = X[s * NMODEL + k0 + k];
    }
    __syncthreads();

    float2 acc[S_LEN];
#pragma unroll
    for (int s = 0; s < S_LEN; ++s) { acc[s].x = 0.f; acc[s].y = 0.f; }

    const float2* __restrict__ Wp = (const float2*)(W + (size_t)k0 * NMODEL) + col2;

#pragma unroll 8
    for (int k = 0; k < KSLICE; ++k) {
        const float2 w = Wp[(size_t)k * (NMODEL / 2)];
        const float4* __restrict__ xr = (const float4*)&Xs[k][0];
#pragma unroll
        for (int s4 = 0; s4 < 4; ++s4) {
            const float4 xv = xr[s4];
            acc[s4 * 4 + 0].x += xv.x * w.x;  acc[s4 * 4 + 0].y += xv.x * w.y;
            acc[s4 * 4 + 1].x += xv.y * w.x;  acc[s4 * 4 + 1].y += xv.y * w.y;
            acc[s4 * 4 + 2].x += xv.z * w.x;  acc[s4 * 4 + 2].y += xv.z * w.y;
            acc[s4 * 4 + 3].x += xv.w * w.x;  acc[s4 * 4 + 3].y += xv.w * w.y;
        }
    }

    float2* __restrict__ pp =
        (float2*)(part + (size_t)(mat * SPLITK + split) * S_LEN * NMODEL) + col2;
#pragma unroll
    for (int s = 0; s < S_LEN; ++s) pp[(size_t)s * (NMODEL / 2)] = acc[s];
}

// ---------------- Kernel 2: reduce split-K partials ----------------
__global__ __launch_bounds__(256) void qkv_reduce(const float* __restrict__ part,
                                                  float* __restrict__ qkv) {
    const int i4   = blockIdx.x * 256 + threadIdx.x;
    const int flat = i4 * 4;
    const int mat  = flat / (S_LEN * NMODEL);
    const int rem  = flat % (S_LEN * NMODEL);
    float4 sum = {0.f, 0.f, 0.f, 0.f};
#pragma unroll
    for (int sp = 0; sp < SPLITK; ++sp) {
        const float4 v = *(const float4*)(part +
            (size_t)(mat * SPLITK + sp) * (S_LEN * NMODEL) + rem);
        sum.x += v.x; sum.y += v.y; sum.z += v.z; sum.w += v.w;
    }
    *(float4*)(qkv + flat) = sum;
}

// ---------------- Kernel 3: flash-decode partial attention ----------------
// grid = (NCHUNK=32, HHEADS=32), block = 256 (4 waves), CHUNK=256 rows
__global__ __launch_bounds__(256) void attn_partial(const float* __restrict__ qkv,
                                                    const float* __restrict__ cacheK,
                                                    const float* __restrict__ cacheV,
                                                    const int* __restrict__ Pp,
                                                    float* __restrict__ opart,
                                                    float* __restrict__ mstat,
                                                    float* __restrict__ lstat) {
    const int c   = blockIdx.x;
    const int h   = blockIdx.y;
    const int tid = threadIdx.x;
    const int P   = *Pp;

    const float* qb = qkv;
    const float* kb = qkv + S_LEN * NMODEL;
    const float* vb = qkv + 2 * S_LEN * NMODEL;

    __shared__ float q_s[S_LEN][DHEAD];      // 8 KB
    __shared__ float sc[CHUNK][SCPAD];       // 20 KB
    __shared__ float mloc[S_LEN], lloc[S_LEN];

    for (int i = tid; i < S_LEN * DHEAD; i += 256)
        q_s[i >> 7][i & 127] = qb[(i >> 7) * NMODEL + h * DHEAD + (i & 127)];
    __syncthreads();

    // ---- phase 1: scores, quad-split rows for packed 1KB wave loads ----
    {
        const int sub = tid & 3;             // quad lane: owns dims j*16+sub*4..+3
        const int r2  = tid >> 2;            // row slot 0..63

        const float* kr[4];
#pragma unroll
        for (int i = 0; i < 4; ++i) {
            const int gm = c * CHUNK + r2 + 64 * i;
            kr[i] = (gm >= P && gm < P + S_LEN)
                ? kb + (size_t)(gm - P) * NMODEL + h * DHEAD
                : cacheK + ((size_t)h * MCACHE + gm) * DHEAD;
        }

        float acc[4][S_LEN];
#pragma unroll
        for (int i = 0; i < 4; ++i)
#pragma unroll
            for (int s = 0; s < S_LEN; ++s) acc[i][s] = 0.f;

#pragma unroll
        for (int j = 0; j < 8; ++j) {
            float4 kv[4];
#pragma unroll
            for (int i = 0; i < 4; ++i)
                kv[i] = *(const float4*)(kr[i] + j * 16 + sub * 4);
#pragma unroll
            for (int s = 0; s < S_LEN; ++s) {
                const float4 qv = *(const float4*)&q_s[s][j * 16 + sub * 4];
#pragma unroll
                for (int i = 0; i < 4; ++i) {
                    acc[i][s] += kv[i].x * qv.x + kv[i].y * qv.y
                               + kv[i].z * qv.z + kv[i].w * qv.w;
                }
            }
        }
        // quad butterfly completes each dot; then sub==0 writes the row
#pragma unroll
        for (int i = 0; i < 4; ++i) {
#pragma unroll
            for (int s = 0; s < S_LEN; ++s) {
                float v = acc[i][s];
                v += __shfl_xor(v, 1, 64);
                v += __shfl_xor(v, 2, 64);
                acc[i][s] = v;
            }
            if (sub == 0) {
#pragma unroll
                for (int s4 = 0; s4 < 4; ++s4) {
                    float4 v; v.x = acc[i][s4*4+0]; v.y = acc[i][s4*4+1];
                    v.z = acc[i][s4*4+2]; v.w = acc[i][s4*4+3];
                    *(float4*)&sc[r2 + 64 * i][s4 * 4] = v;
                }
            }
        }
    }
    __syncthreads();

    // ---- phase 2: per-s max & sumexp over the chunk; sc -> exp ----
    {
        const int wv = tid >> 6, lane = tid & 63;
#pragma unroll
        for (int si = 0; si < 4; ++si) {
            const int s = wv * 4 + si;
            float mx = -1e30f;
#pragma unroll
            for (int r = 0; r < 4; ++r) mx = fmaxf(mx, sc[lane + 64 * r][s]);
            for (int off = 32; off > 0; off >>= 1) mx = fmaxf(mx, __shfl_xor(mx, off, 64));
            float sum = 0.f;
#pragma unroll
            for (int r = 0; r < 4; ++r) {
                const float e = __expf(sc[lane + 64 * r][s] - mx);
                sc[lane + 64 * r][s] = e;
                sum += e;
            }
            for (int off = 32; off > 0; off >>= 1) sum += __shfl_xor(sum, off, 64);
            if (lane == 0) { mloc[s] = mx; lloc[s] = sum; }
        }
    }
    __syncthreads();

    // ---- phase 3: o[s][d] = sum_m p*V ; thread = (s, d-oct), uniform m loop ----
    {
        const int s  = tid >> 4;
        const int d0 = (tid & 15) * 8;
        float a[8];
#pragma unroll
        for (int j = 0; j < 8; ++j) a[j] = 0.f;

        for (int m = 0; m < CHUNK; ++m) {
            const int gm = c * CHUNK + m;                 // wave-uniform
            const float* vr = (gm >= P && gm < P + S_LEN)
                ? vb + (size_t)(gm - P) * NMODEL + h * DHEAD
                : cacheV + ((size_t)h * MCACHE + gm) * DHEAD;
            const float p = sc[m][s];                     // LDS broadcast
            const float4 v0 = *(const float4*)(vr + d0);
            const float4 v1 = *(const float4*)(vr + d0 + 4);
            a[0] += p * v0.x; a[1] += p * v0.y; a[2] += p * v0.z; a[3] += p * v0.w;
            a[4] += p * v1.x; a[5] += p * v1.y; a[6] += p * v1.z; a[7] += p * v1.w;
        }
        const size_t ob = (((size_t)h * NCHUNK + c) * S_LEN + s) * DHEAD + d0;
        float4 w0; w0.x = a[0]; w0.y = a[1]; w0.z = a[2]; w0.w = a[3];
        float4 w1; w1.x = a[4]; w1.y = a[5]; w1.z = a[6]; w1.w = a[7];
        *(float4*)(opart + ob)     = w0;
        *(float4*)(opart + ob + 4) = w1;
    }
    if (tid < S_LEN) {
        mstat[((size_t)h * NCHUNK + c) * S_LEN + tid] = mloc[tid];
        lstat[((size_t)h * NCHUNK + c) * S_LEN + tid] = lloc[tid];
    }
}

// ---------------- Kernel 4: combine chunk partials ----------------
__global__ __launch_bounds__(128) void attn_combine(const float* __restrict__ opart,
                                                    const float* __restrict__ mstat,
                                                    const float* __restrict__ lstat,
                                                    float* __restrict__ out) {
    const int d = threadIdx.x;
    const int s = blockIdx.x;
    const int h = blockIdx.y;

    float gmax = -1e30f;
    for (int c = 0; c < NCHUNK; ++c)
        gmax = fmaxf(gmax, mstat[((size_t)h * NCHUNK + c) * S_LEN + s]);

    float L = 0.f, o = 0.f;
    for (int c = 0; c < NCHUNK; ++c) {
        const size_t si = (size_t)h * NCHUNK * S_LEN + (size_t)c * S_LEN + s;
        const float w = __expf(mstat[si] - gmax);
        L += lstat[si] * w;
        o += w * opart[si * DHEAD + d];
    }
    out[((size_t)h * S_LEN + s) * DHEAD + d] = o / L;
}

extern "C" void kernel_launch(void* const* d_in, const int* in_sizes, int n_in,
                              void* d_out, int out_size, void* d_ws, size_t ws_size,
                              hipStream_t stream) {
    const float* X      = (const float*)d_in[0];
    const float* Wq     = (const float*)d_in[1];
    const float* Wk     = (const float*)d_in[2];
    const float* Wv     = (const float*)d_in[3];
    const float* cacheK = (const float*)d_in[4];
    const float* cacheV = (const float*)d_in[5];
    const int*   P      = (const int*)d_in[6];
    float* out = (float*)d_out;
    float* ws  = (float*)d_ws;

    float* qkv   = ws;                                   // 3*16*4096
    float* part  = qkv + 3 * S_LEN * NMODEL;             // 3*16*16*4096
    float* opart = part;                                 // aliases (dead after reduce)
    float* mstat = opart + (size_t)HHEADS * NCHUNK * S_LEN * DHEAD;
    float* lstat = mstat + (size_t)HHEADS * NCHUNK * S_LEN;

    qkv_gemm<<<dim3(8, SPLITK, 3), 256, 0, stream>>>(X, Wq, Wk, Wv, part);
    qkv_reduce<<<(3 * S_LEN * NMODEL / 4) / 256, 256, 0, stream>>>(part, qkv);
    attn_partial<<<dim3(NCHUNK, HHEADS), 256, 0, stream>>>(qkv, cacheK, cacheV, P,
                                                           opart, mstat, lstat);
    attn_combine<<<dim3(S_LEN, HHEADS), DHEAD, 0, stream>>>(opart, mstat, lstat, out);
}

// Round 4
// 271.272 us; speedup vs baseline: 2.7604x; 2.7604x over previous
//
#include <hip/hip_runtime.h>

#define S_LEN 16
#define NMODEL 4096
#define DHEAD 128
#define HHEADS 32
#define MCACHE 8192
#define SPLITK 16
#define KSLICE (NMODEL / SPLITK)   // 256
#define CHUNK 64                   // rows per block = one row per thread-quad... (64 rows, 256 thr)
#define NCHUNK (MCACHE / CHUNK)    // 128
#define SCPAD 17                   // odd stride -> conflict-free column reads

// ---------------- Kernel 1: split-K partial QKV projection ----------------
__global__ __launch_bounds__(256) void qkv_gemm(const float* __restrict__ X,
                                                const float* __restrict__ Wq,
                                                const float* __restrict__ Wk,
                                                const float* __restrict__ Wv,
                                                float* __restrict__ part) {
    const int tid   = threadIdx.x;
    const int col2  = blockIdx.x * 256 + tid;
    const int split = blockIdx.y;
    const int mat   = blockIdx.z;
    const float* __restrict__ W = (mat == 0) ? Wq : (mat == 1) ? Wk : Wv;
    const int k0 = split * KSLICE;

    __shared__ float Xs[KSLICE][S_LEN];
    for (int i = tid; i < KSLICE * S_LEN; i += 256) {
        const int s = i & 15, k = i >> 4;
        Xs[k][s] = X[s * NMODEL + k0 + k];
    }
    __syncthreads();

    float2 acc[S_LEN];
#pragma unroll
    for (int s = 0; s < S_LEN; ++s) { acc[s].x = 0.f; acc[s].y = 0.f; }

    const float2* __restrict__ Wp = (const float2*)(W + (size_t)k0 * NMODEL) + col2;

#pragma unroll 8
    for (int k = 0; k < KSLICE; ++k) {
        const float2 w = Wp[(size_t)k * (NMODEL / 2)];
        const float4* __restrict__ xr = (const float4*)&Xs[k][0];
#pragma unroll
        for (int s4 = 0; s4 < 4; ++s4) {
            const float4 xv = xr[s4];
            acc[s4 * 4 + 0].x += xv.x * w.x;  acc[s4 * 4 + 0].y += xv.x * w.y;
            acc[s4 * 4 + 1].x += xv.y * w.x;  acc[s4 * 4 + 1].y += xv.y * w.y;
            acc[s4 * 4 + 2].x += xv.z * w.x;  acc[s4 * 4 + 2].y += xv.z * w.y;
            acc[s4 * 4 + 3].x += xv.w * w.x;  acc[s4 * 4 + 3].y += xv.w * w.y;
        }
    }

    float2* __restrict__ pp =
        (float2*)(part + (size_t)(mat * SPLITK + split) * S_LEN * NMODEL) + col2;
#pragma unroll
    for (int s = 0; s < S_LEN; ++s) pp[(size_t)s * (NMODEL / 2)] = acc[s];
}

// ---------------- Kernel 2: reduce split-K partials ----------------
__global__ __launch_bounds__(256) void qkv_reduce(const float* __restrict__ part,
                                                  float* __restrict__ qkv) {
    const int i4   = blockIdx.x * 256 + threadIdx.x;
    const int flat = i4 * 4;
    const int mat  = flat / (S_LEN * NMODEL);
    const int rem  = flat % (S_LEN * NMODEL);
    float4 sum = {0.f, 0.f, 0.f, 0.f};
#pragma unroll
    for (int sp = 0; sp < SPLITK; ++sp) {
        const float4 v = *(const float4*)(part +
            (size_t)(mat * SPLITK + sp) * (S_LEN * NMODEL) + rem);
        sum.x += v.x; sum.y += v.y; sum.z += v.z; sum.w += v.w;
    }
    *(float4*)(qkv + flat) = sum;
}

// ---------------- Kernel 3: flash-decode partial attention ----------------
// grid = (NCHUNK=128, HHEADS=32), block = 256 (4 waves). 64 cache rows/block.
// Phase 1: thread quad (row = tid>>2, sub = tid&3) -> wave instr touches
// 16 fully-consumed 64B lines. acc[16] only -> low VGPR.
__global__ __launch_bounds__(256) void attn_partial(const float* __restrict__ qkv,
                                                    const float* __restrict__ cacheK,
                                                    const float* __restrict__ cacheV,
                                                    const int* __restrict__ Pp,
                                                    float* __restrict__ opart,
                                                    float* __restrict__ mstat,
                                                    float* __restrict__ lstat) {
    const int c   = blockIdx.x;
    const int h   = blockIdx.y;
    const int tid = threadIdx.x;
    const int P   = *Pp;

    const float* qb = qkv;
    const float* kb = qkv + S_LEN * NMODEL;
    const float* vb = qkv + 2 * S_LEN * NMODEL;

    __shared__ float q_s[S_LEN][DHEAD];      // 8 KB
    __shared__ float sc[CHUNK][SCPAD];       // 4.3 KB
    __shared__ float mloc[S_LEN], lloc[S_LEN];

    for (int i = tid; i < S_LEN * DHEAD; i += 256)
        q_s[i >> 7][i & 127] = qb[(i >> 7) * NMODEL + h * DHEAD + (i & 127)];
    __syncthreads();

    // ---- phase 1: scores (one row per thread-quad) ----
    {
        const int sub = tid & 3;             // owns dims j*16 + sub*4 .. +3
        const int r   = tid >> 2;            // row 0..63
        const int gm  = c * CHUNK + r;
        const float* kr = (gm >= P && gm < P + S_LEN)
            ? kb + (size_t)(gm - P) * NMODEL + h * DHEAD       // virtual cache write
            : cacheK + ((size_t)h * MCACHE + gm) * DHEAD;

        float acc[S_LEN];
#pragma unroll
        for (int s = 0; s < S_LEN; ++s) acc[s] = 0.f;

#pragma unroll
        for (int j = 0; j < 8; ++j) {
            const float4 kv = *(const float4*)(kr + j * 16 + sub * 4);
#pragma unroll
            for (int s = 0; s < S_LEN; ++s) {
                const float4 qv = *(const float4*)&q_s[s][j * 16 + sub * 4];
                acc[s] += kv.x * qv.x + kv.y * qv.y + kv.z * qv.z + kv.w * qv.w;
            }
        }
#pragma unroll
        for (int s = 0; s < S_LEN; ++s) {
            float v = acc[s];
            v += __shfl_xor(v, 1, 64);
            v += __shfl_xor(v, 2, 64);
            acc[s] = v;
        }
        if (sub == 0) {
#pragma unroll
            for (int s = 0; s < S_LEN; ++s) sc[r][s] = acc[s];  // 16 banks, no conflict
        }
    }
    __syncthreads();

    // ---- phase 2: per-s max & sumexp (64 rows == 64 lanes) ----
    {
        const int wv = tid >> 6, lane = tid & 63;
#pragma unroll
        for (int si = 0; si < 4; ++si) {
            const int s = wv * 4 + si;
            float v  = sc[lane][s];          // stride 17 -> conflict-free
            float mx = v;
            for (int off = 32; off > 0; off >>= 1) mx = fmaxf(mx, __shfl_xor(mx, off, 64));
            const float e = __expf(v - mx);
            sc[lane][s] = e;
            float sum = e;
            for (int off = 32; off > 0; off >>= 1) sum += __shfl_xor(sum, off, 64);
            if (lane == 0) { mloc[s] = mx; lloc[s] = sum; }
        }
    }
    __syncthreads();

    // ---- phase 3: o[s][d] = sum_m p*V ; thread = (s, d-oct), uniform m ----
    {
        const int s  = tid >> 4;
        const int d0 = (tid & 15) * 8;
        float a[8];
#pragma unroll
        for (int j = 0; j < 8; ++j) a[j] = 0.f;

        for (int m = 0; m < CHUNK; ++m) {
            const int gm = c * CHUNK + m;                 // wave-uniform
            const float* vr = (gm >= P && gm < P + S_LEN)
                ? vb + (size_t)(gm - P) * NMODEL + h * DHEAD
                : cacheV + ((size_t)h * MCACHE + gm) * DHEAD;
            const float p = sc[m][s];                     // LDS broadcast
            const float4 v0 = *(const float4*)(vr + d0);
            const float4 v1 = *(const float4*)(vr + d0 + 4);
            a[0] += p * v0.x; a[1] += p * v0.y; a[2] += p * v0.z; a[3] += p * v0.w;
            a[4] += p * v1.x; a[5] += p * v1.y; a[6] += p * v1.z; a[7] += p * v1.w;
        }
        const size_t ob = (((size_t)h * NCHUNK + c) * S_LEN + s) * DHEAD + d0;
        float4 w0; w0.x = a[0]; w0.y = a[1]; w0.z = a[2]; w0.w = a[3];
        float4 w1; w1.x = a[4]; w1.y = a[5]; w1.z = a[6]; w1.w = a[7];
        *(float4*)(opart + ob)     = w0;
        *(float4*)(opart + ob + 4) = w1;
    }
    if (tid < S_LEN) {
        mstat[((size_t)h * NCHUNK + c) * S_LEN + tid] = mloc[tid];
        lstat[((size_t)h * NCHUNK + c) * S_LEN + tid] = lloc[tid];
    }
}

// ---------------- Kernel 4: combine chunk partials ----------------
__global__ __launch_bounds__(128) void attn_combine(const float* __restrict__ opart,
                                                    const float* __restrict__ mstat,
                                                    const float* __restrict__ lstat,
                                                    float* __restrict__ out) {
    const int d = threadIdx.x;
    const int s = blockIdx.x;
    const int h = blockIdx.y;

    float gmax = -1e30f;
    for (int c = 0; c < NCHUNK; ++c)
        gmax = fmaxf(gmax, mstat[((size_t)h * NCHUNK + c) * S_LEN + s]);

    float L = 0.f, o = 0.f;
    for (int c = 0; c < NCHUNK; ++c) {
        const size_t si = (size_t)h * NCHUNK * S_LEN + (size_t)c * S_LEN + s;
        const float w = __expf(mstat[si] - gmax);
        L += lstat[si] * w;
        o += w * opart[si * DHEAD + d];
    }
    out[((size_t)h * S_LEN + s) * DHEAD + d] = o / L;
}

extern "C" void kernel_launch(void* const* d_in, const int* in_sizes, int n_in,
                              void* d_out, int out_size, void* d_ws, size_t ws_size,
                              hipStream_t stream) {
    const float* X      = (const float*)d_in[0];
    const float* Wq     = (const float*)d_in[1];
    const float* Wk     = (const float*)d_in[2];
    const float* Wv     = (const float*)d_in[3];
    const float* cacheK = (const float*)d_in[4];
    const float* cacheV = (const float*)d_in[5];
    const int*   P      = (const int*)d_in[6];
    float* out = (float*)d_out;
    float* ws  = (float*)d_ws;

    float* qkv   = ws;                                   // 3*16*4096
    float* part  = qkv + 3 * S_LEN * NMODEL;             // 3*16*16*4096 = 12.6M floats
    float* opart = part;                                 // aliases; 32*128*16*128 = 8.4M
    float* mstat = opart + (size_t)HHEADS * NCHUNK * S_LEN * DHEAD;
    float* lstat = mstat + (size_t)HHEADS * NCHUNK * S_LEN;

    qkv_gemm<<<dim3(8, SPLITK, 3), 256, 0, stream>>>(X, Wq, Wk, Wv, part);
    qkv_reduce<<<(3 * S_LEN * NMODEL / 4) / 256, 256, 0, stream>>>(part, qkv);
    attn_partial<<<dim3(NCHUNK, HHEADS), 256, 0, stream>>>(qkv, cacheK, cacheV, P,
                                                           opart, mstat, lstat);
    attn_combine<<<dim3(S_LEN, HHEADS), DHEAD, 0, stream>>>(opart, mstat, lstat, out);
}